// Round 1
// baseline (163.440 us; speedup 1.0000x reference)
//
#include <hip/hip_runtime.h>
#include <hip/hip_bf16.h>
#include <math.h>

typedef unsigned short u16;
typedef unsigned char u8;
typedef unsigned int u32;
typedef long long i64;
typedef __attribute__((ext_vector_type(4))) float f32x4;

// -------------------------------------------------- fp32 -> fp8 e4m3 (x16 pre-scale)
// l2-normed inputs: |x| <~ 0.3 -> x*16 in [~0.01, 4.8]: full mantissa, no saturation.
// Dequant folded into gemm epilogue (divide by 256*temp).
//
// K-PERMUTED OUTPUT: within each 128-byte K-block, byte (32s + 8f + b) of the
// logical row is stored at (32f + 8s + b)  [s,f in 0..3, b in 0..7]. Applied to
// BOTH A and B -> dot products unchanged (R9-verified technique). This makes a
// lane's two MFMA sub-step operands contiguous 16B chunks in LDS.
__global__ void cvt_fused(const float* __restrict__ F, const float* __restrict__ T,
                          u32* __restrict__ Fb, u32* __restrict__ Tb,
                          float* __restrict__ out) {
    const int idx = blockIdx.x * blockDim.x + threadIdx.x;
    if (idx == 0) out[0] = 0.f;
    const float* s;
    u32* d;
    int i;
    if (idx < 65536) { s = F; d = Fb; i = idx; }
    else             { s = T; d = Tb; i = idx - 65536; }
    const float4 v0 = *(const float4*)(s + (size_t)i * 8);
    const float4 v1 = *(const float4*)(s + (size_t)i * 8 + 4);
    int lo = __builtin_amdgcn_cvt_pk_fp8_f32(v0.x * 16.f, v0.y * 16.f, 0, false);
    lo     = __builtin_amdgcn_cvt_pk_fp8_f32(v0.z * 16.f, v0.w * 16.f, lo, true);
    int hi = __builtin_amdgcn_cvt_pk_fp8_f32(v1.x * 16.f, v1.y * 16.f, 0, false);
    hi     = __builtin_amdgcn_cvt_pk_fp8_f32(v1.z * 16.f, v1.w * 16.f, hi, true);
    uint2 o; o.x = (u32)lo; o.y = (u32)hi;
    // permuted destination: row r, in-row byte o -> (t<<7)|(f<<5)|(s<<3)
    const int r  = i >> 6;                 // 64 8-byte groups per 512-elem row
    const int ob = (i & 63) << 3;          // in-row byte offset (multiple of 8)
    const int t  = ob >> 7;
    const int ss = (ob >> 5) & 3;
    const int f  = (ob >> 3) & 3;
    const int o2 = (t << 7) | (f << 5) | (ss << 3);
    ((uint2*)d)[r * 64 + (o2 >> 3)] = o;
}

// ---------------------------------------------------------------- GEMM + max
#define GLB_AS __attribute__((address_space(1)))
#define LDS_AS __attribute__((address_space(3)))

__device__ __forceinline__ void gload_lds16(const void* g, void* l) {
    __builtin_amdgcn_global_load_lds((const GLB_AS void*)g, (LDS_AS void*)l, 16, 0, 0);
}

__device__ __forceinline__ i64 half0(int4 v) { int2 p; p.x = v.x; p.y = v.y; return __builtin_bit_cast(i64, p); }
__device__ __forceinline__ i64 half1(int4 v) { int2 p; p.x = v.z; p.y = v.w; return __builtin_bit_cast(i64, p); }

// A: F fp8 [1024 x 512], B: T fp8 [32768 x 512] (row-major, K-permuted per cvt).
// sim[i*1024+j] = max_{q<32} dot(A[i],B[j*32+q]) / (256*temp)
//
// R11: two latency attacks on the R10 structure (which was latency-bound):
//  (a) XCD bn-SLAB MAPPING: 1-D grid, xcd = bid&7 (round-robin dispatch, m09).
//      Each XCD owns a contiguous 32-bn slab (32*128 rows * 512 B = 2 MB fp8,
//      fits the 4 MB per-XCD L2) and sweeps bm 0..15 over it -> B is fetched
//      from LLC/HBM once per XCD and re-read 16x from L2 (~200 cyc) instead of
//      16x from LLC (~500-700 cyc). A (32 KB/tile) is L2-trivial.
//  (b) DOUBLE-BUFFERED LDS (24 -> 48 KB, 3 blocks/CU): stage(t+1) issues after
//      the iteration barrier and BEFORE compute(t), so load latency hides under
//      the ~300 cyc of MFMA+ds_read; one __syncthreads per K-step instead of
//      two. Hazards: stage(t+1) writes buf[(t+1)&1], last read at compute(t-1),
//      fenced by the barrier at top of iter t; barrier's implicit vmcnt(0) at
//      top of iter t+1 awaits exactly stage(t+1)'s 6 loads.
//
// LDS: row-major 128-B rows; 16B chunk c of row r stored at slot c^(r&7)
// (R4/R9-verified conflict-free). With the cvt K-permutation, lane (frow,fq)
// reads chunks {2fq, 2fq+1}: b128 #0 = sub-steps s0,s1 (dwords 01|23), #1 = s2,s3.
__global__ __launch_bounds__(256, 3)
void gemm_max(const u8* __restrict__ A, const u8* __restrict__ B,
              const float* __restrict__ temp_ptr, float* __restrict__ sim) {
    __shared__ __align__(16) u8 lA[2][64 * 128];    // 2 x  8 KB
    __shared__ __align__(16) u8 lB[2][128 * 128];   // 2 x 16 KB
    const int bid = blockIdx.x;                     // 0..4095
    const int bn  = ((bid & 7) << 5) | ((bid >> 3) & 31);  // XCD slab: xcd*32 + local
    const int bm  = bid >> 8;                               // 0..15, inner sweep
    const int tid  = threadIdx.x;
    const int wave = tid >> 6;
    const int lane = tid & 63;
    const int wm = wave >> 1;       // 0..1: rows wm*32
    const int wn = wave & 1;        // 0..1: cols wn*64

    f32x4 acc[2][4] = {};

    // staging: one glds = 8 rows x 128B. lane -> srow = lane>>3, slot chunk l&7
    // holds global chunk (l&7)^srow.
    const int srow = lane >> 3;
    const int aoff = srow * 512 + (((lane & 7) ^ srow) << 4);   // per-lane global offset
    const u8* gA = A + (size_t)(bm * 64)  * 512 + aoff;         // + ga*4096 + k0
    const u8* gB = B + (size_t)(bn * 128) * 512 + aoff;         // + gb*4096 + k0

    const int frow = lane & 15;
    const int fq   = lane >> 4;
    const int r7   = frow & 7;

#define STAGE(pb, k0)                                                                   \
    do {                                                                                \
        gload_lds16(gA + (wave)     * 4096 + (k0), &lA[pb][(wave)     * 1024]);         \
        gload_lds16(gA + (wave + 4) * 4096 + (k0), &lA[pb][(wave + 4) * 1024]);         \
        _Pragma("unroll")                                                               \
        for (int j = 0; j < 4; ++j)                                                     \
            gload_lds16(gB + (wave + 4 * j) * 4096 + (k0), &lB[pb][(wave + 4 * j) * 1024]); \
    } while (0)

    STAGE(0, 0);
#pragma unroll
    for (int t = 0; t < 4; ++t) {
        __syncthreads();                      // drains stage(t) loads (vmcnt 0)
        if (t < 3) STAGE((t + 1) & 1, (t + 1) * 128);   // prefetch under compute
        const int pb = t & 1;                 // compile-time (loop unrolled)
#pragma unroll
        for (int sp = 0; sp < 2; ++sp) {
            const int coff = (((fq << 1) + sp) ^ r7) << 4;
            int4 aF[2], bF[4];
#pragma unroll
            for (int mt = 0; mt < 2; ++mt)
                aF[mt] = *(const int4*)&lA[pb][(wm * 32 + mt * 16 + frow) * 128 + coff];
#pragma unroll
            for (int nt = 0; nt < 4; ++nt)
                bF[nt] = *(const int4*)&lB[pb][(wn * 64 + nt * 16 + frow) * 128 + coff];
#pragma unroll
            for (int mt = 0; mt < 2; ++mt)
#pragma unroll
                for (int nt = 0; nt < 4; ++nt) {
                    acc[mt][nt] = __builtin_amdgcn_mfma_f32_16x16x32_fp8_fp8(
                        half0(aF[mt]), half0(bF[nt]), acc[mt][nt], 0, 0, 0);
                    acc[mt][nt] = __builtin_amdgcn_mfma_f32_16x16x32_fp8_fp8(
                        half1(aF[mt]), half1(bF[nt]), acc[mt][nt], 0, 0, 0);
                }
        }
    }
#undef STAGE

    // epilogue: C row = bm*64 + wm*32 + mt*16 + fq*4 + rr ; col = bn*128+wn*64+nt*16+(l&15)
    const float inv = 1.0f / (256.0f * (*temp_ptr));
    const int jb = (bn * 128 + wn * 64) >> 5;
#pragma unroll
    for (int mt = 0; mt < 2; ++mt) {
#pragma unroll
        for (int rr = 0; rr < 4; ++rr) {
            float v0 = fmaxf(acc[mt][0][rr], acc[mt][1][rr]);
            float v1 = fmaxf(acc[mt][2][rr], acc[mt][3][rr]);
#pragma unroll
            for (int off = 1; off < 16; off <<= 1) {
                v0 = fmaxf(v0, __shfl_xor(v0, off));
                v1 = fmaxf(v1, __shfl_xor(v1, off));
            }
            if ((lane & 15) == 0) {
                const int row = bm * 64 + wm * 32 + mt * 16 + fq * 4 + rr;
                sim[row * 1024 + jb]     = v0 * inv;
                sim[row * 1024 + jb + 1] = v1 * inv;
            }
        }
    }
}

// ---------------------------------------------------------------- per-row loss
// ONE WAVE PER ROW, zero LDS, zero barriers. Row (1024 fp32) in 16 regs/lane.
__device__ __forceinline__ u32 f2key(float x) {
    u32 b = __float_as_uint(x);
    return (b & 0x80000000u) ? ~b : (b | 0x80000000u);
}
__device__ __forceinline__ float key2f(u32 k) {
    return __uint_as_float((k & 0x80000000u) ? (k & 0x7fffffffu) : ~k);
}

__global__ __launch_bounds__(256)
void row_loss(const float* __restrict__ sim, float* __restrict__ out) {
    const int tid = threadIdx.x;
    const int lane = tid & 63;
    const int wv = tid >> 6;
    const int i = blockIdx.x * 4 + wv;          // row index

    float v[16];
    const float4* rp = (const float4*)(sim + (size_t)i * 1024);
#pragma unroll
    for (int t = 0; t < 4; ++t) {
        float4 f = rp[t * 64 + lane];
        v[t * 4 + 0] = f.x; v[t * 4 + 1] = f.y; v[t * 4 + 2] = f.z; v[t * 4 + 3] = f.w;
    }

    const int dslot = ((i >> 8) << 2) | (i & 3);
    const int dlane = (i >> 2) & 63;

    u32 k[16];
#pragma unroll
    for (int t = 0; t < 16; ++t) {
        u32 kk = f2key(v[t]);
        k[t] = (lane == dlane && t == dslot) ? 0u : kk;   // diag -> below any finite key
    }

    float pv = 0.f;
#pragma unroll
    for (int t = 0; t < 16; ++t) if (t == dslot) pv = v[t];
    const float pos = __shfl(pv, dlane);

    float m = v[0];
#pragma unroll
    for (int t = 1; t < 16; ++t) m = fmaxf(m, v[t]);
#pragma unroll
    for (int off = 32; off > 0; off >>= 1) m = fmaxf(m, __shfl_xor(m, off));
    float s = 0.f;
#pragma unroll
    for (int t = 0; t < 16; ++t) s += __expf(v[t] - m);
#pragma unroll
    for (int off = 32; off > 0; off >>= 1) s += __shfl_xor(s, off);
    const float loss_std = m + __logf(s) - pos;

    // binary search: largest x with count(key >= x) >= 512
    u32 lo = 0u, hi = 0xFFFFFFFFu;
    while (lo < hi) {
        const u32 span = hi - lo;
        const u32 mid = lo + (span >> 1) + (span & 1u);
        int cnt = 0;
#pragma unroll
        for (int t = 0; t < 16; ++t) cnt += (k[t] >= mid);
#pragma unroll
        for (int off = 32; off > 0; off >>= 1) cnt += __shfl_xor(cnt, off);
        if (cnt >= 512) lo = mid; else hi = mid - 1;
    }
    const u32 t_key = lo;
    const float tval = key2f(t_key);

    float se = 0.f;
    int cgt = 0;
#pragma unroll
    for (int t = 0; t < 16; ++t) {
        if (k[t] > t_key) { se += __expf(v[t] - m); ++cgt; }
    }
#pragma unroll
    for (int off = 32; off > 0; off >>= 1) se += __shfl_xor(se, off);
#pragma unroll
    for (int off = 32; off > 0; off >>= 1) cgt += __shfl_xor(cgt, off);

    const float sh = se + (float)(512 - cgt) * __expf(tval - m) + __expf(pos - m);
    const float hard = m + __logf(sh) - pos;

    if (lane == 0)
        atomicAdd(out, (loss_std + 0.5f * hard) * (1.0f / 1024.0f));
}

// ---------------------------------------------------------------- launch
extern "C" void kernel_launch(void* const* d_in, const int* in_sizes, int n_in,
                              void* d_out, int out_size, void* d_ws, size_t ws_size,
                              hipStream_t stream) {
    const float* F    = (const float*)d_in[0];   // 1024*512
    const float* T    = (const float*)d_in[1];   // 1024*32*512
    const float* temp = (const float*)d_in[2];   // scalar
    float* out = (float*)d_out;

    char* ws = (char*)d_ws;
    u32*  Fb8 = (u32*)ws;                                   // 0.5 MB fp8
    u32*  Tb8 = (u32*)(ws + (1u << 20));                    // 16 MB fp8
    float* sim = (float*)(ws + (1u << 20) + (32u << 20));   // 4 MB

    cvt_fused<<<8448, 256, 0, stream>>>(F, T, Fb8, Tb8, out);

    gemm_max<<<4096, 256, 0, stream>>>((const u8*)Fb8, (const u8*)Tb8, temp, sim);

    row_loss<<<256, 256, 0, stream>>>(sim, out);
}

// Round 2
// 154.483 us; speedup vs baseline: 1.0580x; 1.0580x over previous
//
#include <hip/hip_runtime.h>
#include <hip/hip_bf16.h>
#include <math.h>

typedef unsigned short u16;
typedef unsigned char u8;
typedef unsigned int u32;
typedef long long i64;
typedef __attribute__((ext_vector_type(4))) float f32x4;

// -------------------------------------------------- fp32 -> fp8 e4m3 (x16 pre-scale)
// l2-normed inputs: |x| <~ 0.3 -> x*16 in [~0.01, 4.8]: full mantissa, no saturation.
// Dequant folded into gemm epilogue (divide by 256*temp).
//
// K-PERMUTED OUTPUT: within each 128-byte K-block, byte (32s + 8f + b) of the
// logical row is stored at (32f + 8s + b)  [s,f in 0..3, b in 0..7]. Applied to
// BOTH A and B -> dot products unchanged (R9-verified technique). This makes a
// lane's two MFMA sub-step operands contiguous 16B chunks in LDS.
__global__ void cvt_fused(const float* __restrict__ F, const float* __restrict__ T,
                          u32* __restrict__ Fb, u32* __restrict__ Tb,
                          float* __restrict__ out) {
    const int idx = blockIdx.x * blockDim.x + threadIdx.x;
    if (idx == 0) out[0] = 0.f;
    const float* s;
    u32* d;
    int i;
    if (idx < 65536) { s = F; d = Fb; i = idx; }
    else             { s = T; d = Tb; i = idx - 65536; }
    const float4 v0 = *(const float4*)(s + (size_t)i * 8);
    const float4 v1 = *(const float4*)(s + (size_t)i * 8 + 4);
    int lo = __builtin_amdgcn_cvt_pk_fp8_f32(v0.x * 16.f, v0.y * 16.f, 0, false);
    lo     = __builtin_amdgcn_cvt_pk_fp8_f32(v0.z * 16.f, v0.w * 16.f, lo, true);
    int hi = __builtin_amdgcn_cvt_pk_fp8_f32(v1.x * 16.f, v1.y * 16.f, 0, false);
    hi     = __builtin_amdgcn_cvt_pk_fp8_f32(v1.z * 16.f, v1.w * 16.f, hi, true);
    uint2 o; o.x = (u32)lo; o.y = (u32)hi;
    // permuted destination: row r, in-row byte o -> (t<<7)|(f<<5)|(s<<3)
    const int r  = i >> 6;                 // 64 8-byte groups per 512-elem row
    const int ob = (i & 63) << 3;          // in-row byte offset (multiple of 8)
    const int t  = ob >> 7;
    const int ss = (ob >> 5) & 3;
    const int f  = (ob >> 3) & 3;
    const int o2 = (t << 7) | (f << 5) | (ss << 3);
    ((uint2*)d)[r * 64 + (o2 >> 3)] = o;
}

// ---------------------------------------------------------------- GEMM + max
#define GLB_AS __attribute__((address_space(1)))
#define LDS_AS __attribute__((address_space(3)))

__device__ __forceinline__ void gload_lds16(const void* g, void* l) {
    __builtin_amdgcn_global_load_lds((const GLB_AS void*)g, (LDS_AS void*)l, 16, 0, 0);
}

__device__ __forceinline__ i64 half0(int4 v) { int2 p; p.x = v.x; p.y = v.y; return __builtin_bit_cast(i64, p); }
__device__ __forceinline__ i64 half1(int4 v) { int2 p; p.x = v.z; p.y = v.w; return __builtin_bit_cast(i64, p); }

// A: F fp8 [1024 x 512], B: T fp8 [32768 x 512] (row-major, K-permuted per cvt).
// sim[i*1024+j] = max_{q<32} dot(A[i],B[j*32+q]) / (256*temp)
//
// R12: R11 post-mortem showed latency-bound with LDS pipe the top demand
// (~2290 cyc/block vs MFMA ~1240) and occupancy the R11 regression cause
// (dbuf cost 4->3 blocks/CU). Fix = ARITHMETIC INTENSITY, not scheduling:
//  - wave tile 32x64 -> 64x64 (4x4 grid of 16x16x32, acc=64 VGPR): LDS bytes
//    per FLOP drop 1.5x; per-K-step balance flips MFMA-dominant
//    (MFMA ~1240 cyc vs LDS ~750 cyc per block).
//  - block tile 128x128, BK=128, SINGLE-buffered 32 KB LDS -> back to
//    4 blocks/CU (16 waves) per R10, which beat R11's 3-block dbuf.
//  - XCD bn-slab kept (2 MB B-slab/XCD, L2-resident, re-read 8x).
//
// LDS: row-major 128-B rows; 16B chunk c of row r stored at slot c^(r&7)
// (R4/R9-verified conflict-free). With the cvt K-permutation, lane (frow,fq)
// reads chunks {2fq, 2fq+1}: b128 #0 = sub-steps s0,s1 (dwords 01|23), #1 = s2,s3.
__global__ __launch_bounds__(256, 4)
void gemm_max(const u8* __restrict__ A, const u8* __restrict__ B,
              const float* __restrict__ temp_ptr, float* __restrict__ sim) {
    __shared__ __align__(16) u8 lA[128 * 128];   // 16 KB
    __shared__ __align__(16) u8 lB[128 * 128];   // 16 KB
    const int bid = blockIdx.x;                  // 0..2047
    const int bn  = ((bid & 7) << 5) | ((bid >> 3) & 31);  // XCD slab: xcd*32 + local
    const int bm  = bid >> 8;                               // 0..7, inner sweep
    const int tid  = threadIdx.x;
    const int wave = tid >> 6;
    const int lane = tid & 63;
    const int wm = wave >> 1;       // 0..1: rows wm*64
    const int wn = wave & 1;        // 0..1: cols wn*64

    f32x4 acc[4][4] = {};           // 64 VGPRs

    // staging: one glds = 8 rows x 128B. lane -> srow = lane>>3, slot chunk l&7
    // holds global chunk (l&7)^srow.
    const int srow = lane >> 3;
    const int aoff = srow * 512 + (((lane & 7) ^ srow) << 4);   // per-lane global offset
    const u8* gA = A + (size_t)(bm * 128) * 512 + aoff;         // + grp*4096 + k0
    const u8* gB = B + (size_t)(bn * 128) * 512 + aoff;         // + grp*4096 + k0

    const int frow = lane & 15;
    const int fq   = lane >> 4;
    const int r7   = frow & 7;

    for (int k0 = 0; k0 < 512; k0 += 128) {
        // A and B each: 16 groups of 8 rows; this wave does groups wave+4g.
#pragma unroll
        for (int g = 0; g < 4; ++g)
            gload_lds16(gA + (wave + 4 * g) * 4096 + k0, lA + (wave + 4 * g) * 1024);
#pragma unroll
        for (int g = 0; g < 4; ++g)
            gload_lds16(gB + (wave + 4 * g) * 4096 + k0, lB + (wave + 4 * g) * 1024);
        __syncthreads();

#pragma unroll
        for (int sp = 0; sp < 2; ++sp) {
            const int coff = (((fq << 1) + sp) ^ r7) << 4;
            int4 aF[4], bF[4];
#pragma unroll
            for (int mt = 0; mt < 4; ++mt)
                aF[mt] = *(const int4*)&lA[(wm * 64 + mt * 16 + frow) * 128 + coff];
#pragma unroll
            for (int nt = 0; nt < 4; ++nt)
                bF[nt] = *(const int4*)&lB[(wn * 64 + nt * 16 + frow) * 128 + coff];
#pragma unroll
            for (int mt = 0; mt < 4; ++mt)
#pragma unroll
                for (int nt = 0; nt < 4; ++nt) {
                    acc[mt][nt] = __builtin_amdgcn_mfma_f32_16x16x32_fp8_fp8(
                        half0(aF[mt]), half0(bF[nt]), acc[mt][nt], 0, 0, 0);
                    acc[mt][nt] = __builtin_amdgcn_mfma_f32_16x16x32_fp8_fp8(
                        half1(aF[mt]), half1(bF[nt]), acc[mt][nt], 0, 0, 0);
                }
        }
        __syncthreads();
    }

    // epilogue: C row = bm*128 + wm*64 + mt*16 + fq*4 + rr ;
    //           col   = bn*128 + wn*64 + nt*16 + (l&15);  j = col>>5
    const float inv = 1.0f / (256.0f * (*temp_ptr));
    const int jb = (bn * 128 + wn * 64) >> 5;
#pragma unroll
    for (int mt = 0; mt < 4; ++mt) {
#pragma unroll
        for (int rr = 0; rr < 4; ++rr) {
            float v0 = fmaxf(acc[mt][0][rr], acc[mt][1][rr]);
            float v1 = fmaxf(acc[mt][2][rr], acc[mt][3][rr]);
#pragma unroll
            for (int off = 1; off < 16; off <<= 1) {
                v0 = fmaxf(v0, __shfl_xor(v0, off));
                v1 = fmaxf(v1, __shfl_xor(v1, off));
            }
            if ((lane & 15) == 0) {
                const int row = bm * 128 + wm * 64 + mt * 16 + fq * 4 + rr;
                sim[row * 1024 + jb]     = v0 * inv;
                sim[row * 1024 + jb + 1] = v1 * inv;
            }
        }
    }
}

// ---------------------------------------------------------------- per-row loss
// ONE WAVE PER ROW, zero LDS, zero barriers. Row (1024 fp32) in 16 regs/lane.
__device__ __forceinline__ u32 f2key(float x) {
    u32 b = __float_as_uint(x);
    return (b & 0x80000000u) ? ~b : (b | 0x80000000u);
}
__device__ __forceinline__ float key2f(u32 k) {
    return __uint_as_float((k & 0x80000000u) ? (k & 0x7fffffffu) : ~k);
}

__global__ __launch_bounds__(256)
void row_loss(const float* __restrict__ sim, float* __restrict__ out) {
    const int tid = threadIdx.x;
    const int lane = tid & 63;
    const int wv = tid >> 6;
    const int i = blockIdx.x * 4 + wv;          // row index

    float v[16];
    const float4* rp = (const float4*)(sim + (size_t)i * 1024);
#pragma unroll
    for (int t = 0; t < 4; ++t) {
        float4 f = rp[t * 64 + lane];
        v[t * 4 + 0] = f.x; v[t * 4 + 1] = f.y; v[t * 4 + 2] = f.z; v[t * 4 + 3] = f.w;
    }

    const int dslot = ((i >> 8) << 2) | (i & 3);
    const int dlane = (i >> 2) & 63;

    u32 k[16];
#pragma unroll
    for (int t = 0; t < 16; ++t) {
        u32 kk = f2key(v[t]);
        k[t] = (lane == dlane && t == dslot) ? 0u : kk;   // diag -> below any finite key
    }

    float pv = 0.f;
#pragma unroll
    for (int t = 0; t < 16; ++t) if (t == dslot) pv = v[t];
    const float pos = __shfl(pv, dlane);

    float m = v[0];
#pragma unroll
    for (int t = 1; t < 16; ++t) m = fmaxf(m, v[t]);
#pragma unroll
    for (int off = 32; off > 0; off >>= 1) m = fmaxf(m, __shfl_xor(m, off));
    float s = 0.f;
#pragma unroll
    for (int t = 0; t < 16; ++t) s += __expf(v[t] - m);
#pragma unroll
    for (int off = 32; off > 0; off >>= 1) s += __shfl_xor(s, off);
    const float loss_std = m + __logf(s) - pos;

    // binary search: largest x with count(key >= x) >= 512
    u32 lo = 0u, hi = 0xFFFFFFFFu;
    while (lo < hi) {
        const u32 span = hi - lo;
        const u32 mid = lo + (span >> 1) + (span & 1u);
        int cnt = 0;
#pragma unroll
        for (int t = 0; t < 16; ++t) cnt += (k[t] >= mid);
#pragma unroll
        for (int off = 32; off > 0; off >>= 1) cnt += __shfl_xor(cnt, off);
        if (cnt >= 512) lo = mid; else hi = mid - 1;
    }
    const u32 t_key = lo;
    const float tval = key2f(t_key);

    float se = 0.f;
    int cgt = 0;
#pragma unroll
    for (int t = 0; t < 16; ++t) {
        if (k[t] > t_key) { se += __expf(v[t] - m); ++cgt; }
    }
#pragma unroll
    for (int off = 32; off > 0; off >>= 1) se += __shfl_xor(se, off);
#pragma unroll
    for (int off = 32; off > 0; off >>= 1) cgt += __shfl_xor(cgt, off);

    const float sh = se + (float)(512 - cgt) * __expf(tval - m) + __expf(pos - m);
    const float hard = m + __logf(sh) - pos;

    if (lane == 0)
        atomicAdd(out, (loss_std + 0.5f * hard) * (1.0f / 1024.0f));
}

// ---------------------------------------------------------------- launch
extern "C" void kernel_launch(void* const* d_in, const int* in_sizes, int n_in,
                              void* d_out, int out_size, void* d_ws, size_t ws_size,
                              hipStream_t stream) {
    const float* F    = (const float*)d_in[0];   // 1024*512
    const float* T    = (const float*)d_in[1];   // 1024*32*512
    const float* temp = (const float*)d_in[2];   // scalar
    float* out = (float*)d_out;

    char* ws = (char*)d_ws;
    u32*  Fb8 = (u32*)ws;                                   // 0.5 MB fp8
    u32*  Tb8 = (u32*)(ws + (1u << 20));                    // 16 MB fp8
    float* sim = (float*)(ws + (1u << 20) + (32u << 20));   // 4 MB

    cvt_fused<<<8448, 256, 0, stream>>>(F, T, Fb8, Tb8, out);

    gemm_max<<<2048, 256, 0, stream>>>((const u8*)Fb8, (const u8*)Tb8, temp, sim);

    row_loss<<<256, 256, 0, stream>>>(sim, out);
}